// Round 11
// baseline (283.110 us; speedup 1.0000x reference)
//
#include <hip/hip_runtime.h>

#define N_PTS 1000000
#define H_DIM 200
#define W_DIM 70400
#define FILL_V -9999999.0f

typedef float v2f __attribute__((ext_vector_type(2)));

__device__ __forceinline__ v2f fma2(v2f a, v2f b, v2f c) {
    return __builtin_elementwise_fma(a, b, c);   // -> v_pk_fma_f32 on gfx950
}

// ---------------------------------------------------------------------------
// Kernel A: per-pair MLP (4->18->36->36->1), TWO points per thread, k-packed
// v2f math (v_pk_fma_f32). Weights stream wave-uniform from global as
// s_load_dwordx16 (R9/R10 proven: LDS=0, SGPR=112, no scratch). R10 showed
// the kernel is latency-bound on that scalar stream (VALUBusy 37%): the
// ~96-dword SGPR window feeds only 8 pk_fma per chunk. With 2 points, each
// weight chunk feeds 16 pk_fma -> double work per outstanding load, half the
// waves. Live set: h1 18 v2f + h2 36 v2f + io ~= 125 VGPR, within the
// __launch_bounds__(256,3) budget (~168) -- R4's 2-pt spill was a ~190-float
// SCALAR live set at a 128 budget. Layer 4 fused into layer 3 (h3 never
// materialized).
// List entry: .x = value bits, .y = (point_index << 8) | row  (row<200<256).
// Last-write-wins scatter: point survives iff no LATER point hit (row,col).
// ---------------------------------------------------------------------------
__global__ void __launch_bounds__(256, 3) mlp_scatter_kernel(
    const float* __restrict__ input,        // [4][N]
    const int* __restrict__ tindex,         // [N][2] int32 (row, col)
    const float* __restrict__ w1, const float* __restrict__ b1,
    const float* __restrict__ w2, const float* __restrict__ b2,
    const float* __restrict__ w3, const float* __restrict__ b3,
    const float* __restrict__ w4, const float* __restrict__ b4,
    int* __restrict__ counts,               // [W]
    uint2* __restrict__ list,               // [W][maxk]
    int maxk)
{
    // empty-branch (reference: tensor_index[0,0] == -1 -> no scatter)
    if (tindex[0] == -1) return;

    const int pr = blockIdx.x * 256 + threadIdx.x;  // points 2*pr, 2*pr+1
    if (2 * pr >= N_PTS) return;

    const v2f* __restrict__ w1v = (const v2f*)w1;   // rows of 4 = 2 v2f
    const v2f* __restrict__ w2v = (const v2f*)w2;   // rows of 18 = 9 v2f
    const v2f* __restrict__ w3v = (const v2f*)w3;   // rows of 36 = 18 v2f

    // channel-major loads: cK = {chK[2pr], chK[2pr+1]}
    const float2 c0 = ((const float2*)(input            ))[pr];
    const float2 c1 = ((const float2*)(input +     N_PTS))[pr];
    const float2 c2 = ((const float2*)(input + 2 * N_PTS))[pr];
    const float2 c3 = ((const float2*)(input + 3 * N_PTS))[pr];

    const v2f x01a = { c0.x, c1.x }, x23a = { c2.x, c3.x };   // point 0
    const v2f x01b = { c0.y, c1.y }, x23b = { c2.y, c3.y };   // point 1

    // layer 1: 18 outputs, k packed (4 -> 2 pairs)
    v2f h1a[9], h1b[9];
#pragma unroll
    for (int o = 0; o < 18; ++o) {
        const v2f wlo = w1v[o * 2 + 0], whi = w1v[o * 2 + 1];
        v2f acca = { b1[o], 0.0f };
        v2f accb = acca;
        acca = fma2(wlo, x01a, acca); acca = fma2(whi, x23a, acca);
        accb = fma2(wlo, x01b, accb); accb = fma2(whi, x23b, accb);
        const float ha = fmaxf(acca.x + acca.y, 0.0f);
        const float hb = fmaxf(accb.x + accb.y, 0.0f);
        if (o & 1) { h1a[o >> 1].y = ha; h1b[o >> 1].y = hb; }
        else       { h1a[o >> 1].x = ha; h1b[o >> 1].x = hb; }
    }

    // layer 2: 36 outputs, k packed (18 -> 9 pairs)
    v2f h2a[18], h2b[18];
#pragma unroll
    for (int o = 0; o < 36; ++o) {
        v2f acca = { b2[o], 0.0f };
        v2f accb = acca;
#pragma unroll
        for (int q = 0; q < 9; ++q) {
            const v2f wv = w2v[o * 9 + q];          // shared weight chunk
            acca = fma2(wv, h1a[q], acca);
            accb = fma2(wv, h1b[q], accb);
        }
        const float ha = fmaxf(acca.x + acca.y, 0.0f);
        const float hb = fmaxf(accb.x + accb.y, 0.0f);
        if (o & 1) { h2a[o >> 1].y = ha; h2b[o >> 1].y = hb; }
        else       { h2a[o >> 1].x = ha; h2b[o >> 1].x = hb; }
    }

    // layer 3 (k packed, 36 -> 18 pairs) with layer 4 fused
    float va = b4[0], vb = b4[0];
#pragma unroll
    for (int o = 0; o < 36; ++o) {
        v2f acca = { b3[o], 0.0f };
        v2f accb = acca;
#pragma unroll
        for (int q = 0; q < 18; ++q) {
            const v2f wv = w3v[o * 18 + q];
            acca = fma2(wv, h2a[q], acca);
            accb = fma2(wv, h2b[q], accb);
        }
        const float w4o = w4[o];
        va = fmaf(w4o, fmaxf(acca.x + acca.y, 0.0f), va);
        vb = fmaf(w4o, fmaxf(accb.x + accb.y, 0.0f), vb);
    }

    const int4 hw = ((const int4*)tindex)[pr];   // (h0,w0,h1,w1)
    {
        const int pos = atomicAdd(&counts[hw.y], 1);
        if (pos < maxk)
            list[(size_t)hw.y * maxk + pos] =
                make_uint2(__float_as_uint(va),
                           ((unsigned)(2 * pr) << 8) | (unsigned)hw.x);
    }
    {
        const int pos = atomicAdd(&counts[hw.w], 1);
        if (pos < maxk)
            list[(size_t)hw.w * maxk + pos] =
                make_uint2(__float_as_uint(vb),
                           ((unsigned)(2 * pr + 1) << 8) | (unsigned)hw.z);
    }
}

// ---------------------------------------------------------------------------
// Kernel B: block (64,4) = 4 waves, one column per wave. Lane a holds slot a
// (one coalesced load per wave). Dedup via 64-bit per-wave winner table:
// atomicMax(tbl64[row], (key<<32)|value_bits); high word (i<<8|row) orders by
// point index, low word carries the winner's value. After __syncthreads(),
// each lane reads its row's winner VALUE; duplicate reads of the same winner
// are harmless under max. (R4/R5 bug: init must cover all 200 rows -- 64
// lanes need 4 strided passes.) Verified correct R6-R10.
// ---------------------------------------------------------------------------
__global__ void __launch_bounds__(256) colmax_kernel(
    const int* __restrict__ tindex,
    const int* __restrict__ counts,
    const uint2* __restrict__ list,
    float* __restrict__ out,
    int maxk)
{
    __shared__ unsigned long long rowwin[4][200];
    const int lane = threadIdx.x;        // 0..63
    const int y    = threadIdx.y;        // 0..3
    const int w    = blockIdx.x * 4 + y; // column id, always < W_DIM (70400=4*17600)

    const bool empty = (tindex[0] == -1);

    if (blockIdx.x == 0 && lane == 0 && y == 0)
        out[W_DIM] = empty ? 0.0f : 1.0f;    // flag output

    int c = 0;
    if (!empty) {
        c = counts[w];
        if (c > maxk) c = maxk;
    }

    unsigned long long* tbl = rowwin[y];
    tbl[lane]       = 0ull;                  // rows   0.. 63
    tbl[lane + 64]  = 0ull;                  // rows  64..127
    tbl[lane + 128] = 0ull;                  // rows 128..191
    if (lane < 8) tbl[lane + 192] = 0ull;    // rows 192..199
    __syncthreads();

    uint2 e = make_uint2(0u, 0u);
    const bool have = (lane < c);
    if (have) {
        e = list[(size_t)w * maxk + lane];
        const unsigned long long key64 =
            ((unsigned long long)e.y << 32) | (unsigned long long)e.x;
        atomicMax(&tbl[e.y & 0xFFu], key64);
    }
    __syncthreads();

    float v = FILL_V;
    if (have) {
        const unsigned long long winner = tbl[e.y & 0xFFu];
        v = __uint_as_float((unsigned)(winner & 0xFFFFFFFFull));
    }
#pragma unroll
    for (int off = 32; off > 0; off >>= 1)
        v = fmaxf(v, __shfl_down(v, off, 64));

    if (lane == 0) out[w] = v;
}

extern "C" void kernel_launch(void* const* d_in, const int* in_sizes, int n_in,
                              void* d_out, int out_size, void* d_ws, size_t ws_size,
                              hipStream_t stream) {
    const float* input  = (const float*)d_in[0];
    const int*   tindex = (const int*)d_in[1];   // int32 on device
    const float* w1 = (const float*)d_in[2];
    const float* b1 = (const float*)d_in[3];
    const float* w2 = (const float*)d_in[4];
    const float* b2 = (const float*)d_in[5];
    const float* w3 = (const float*)d_in[6];
    const float* b3 = (const float*)d_in[7];
    const float* w4 = (const float*)d_in[8];
    const float* b4 = (const float*)d_in[9];
    float* out = (float*)d_out;

    // workspace: counts [70400 int] | list [70400][maxk] uint2
    int*   counts = (int*)d_ws;
    uint2* list   = (uint2*)((char*)d_ws + (size_t)W_DIM * sizeof(int));

    size_t avail = (ws_size > (size_t)W_DIM * sizeof(int))
                       ? ws_size - (size_t)W_DIM * sizeof(int) : 0;
    int maxk = (int)(avail / ((size_t)W_DIM * sizeof(uint2)));
    if (maxk > 64) maxk = 64;
    if (maxk < 1)  maxk = 1;

    hipMemsetAsync(counts, 0, (size_t)W_DIM * sizeof(int), stream);

    // 2 points per thread -> 500k pair-threads
    const int pairs = N_PTS / 2;
    mlp_scatter_kernel<<<(pairs + 255) / 256, 256, 0, stream>>>(
        input, tindex, w1, b1, w2, b2, w3, b3, w4, b4, counts, list, maxk);

    // one wave per column, 4 waves per block; 70400/4 = 17600 exact blocks
    colmax_kernel<<<W_DIM / 4, dim3(64, 4), 0, stream>>>(
        tindex, counts, list, out, maxk);
}